// Round 3
// baseline (701.730 us; speedup 1.0000x reference)
//
#include <hip/hip_runtime.h>

#define EPS_C 0.05f
#define BLOCK 256
#define CHUNK 8192            /* elems per block: 4 waves x 2048 */
#define FLAG_AGG 1ull
#define FLAG_INC 2ull

typedef int i4 __attribute__((ext_vector_type(4)));
typedef float f4 __attribute__((ext_vector_type(4)));   /* nt-store compatible */

// Zero the lookback descriptors + ticket (graph-capture-safe re-init each replay).
__global__ void k_zero(unsigned long long* __restrict__ p, int n) {
  int i = blockIdx.x * blockDim.x + threadIdx.x;
  if (i < n) p[i] = 0ull;
}

// Single-pass decoupled-lookback scan.
// Block (ticket) b owns elems [b*CHUNK, +CHUNK): load once (NT), nibble-pack
// categories into 4 VGPRs, publish aggregate, lookback for exclusive prefix,
// decode + wave-scan + NT store. Wave w owns contiguous [w*2048, +2048) within
// the chunk; per round a wave touches 1024 contiguous floats (full-line I/O).
__global__ __launch_bounds__(BLOCK) void k_scan_lookback(
    const int* __restrict__ ann, const float* __restrict__ origin,
    const float* __restrict__ bd, const float* __restrict__ d,
    const float* __restrict__ s, const float* __restrict__ inc,
    const float* __restrict__ bi, float* __restrict__ out,
    unsigned long long* __restrict__ desc, unsigned int* __restrict__ ticket,
    int nb) {
  __shared__ float cs[8];
  __shared__ float wsum[4];
  __shared__ float s_carry;
  __shared__ int s_bid;

  const int t = threadIdx.x;
  const int lane = t & 63;
  const int wid = t >> 6;

  if (t == 0) {
    float vbd = *bd, vd = *d, vs = *s, vi = *inc, vbi = *bi;
    cs[0] = 0.0f;                                   // cat 0 (unused)
    cs[1] = fminf(vbd, fminf(0.0f, vd)) - EPS_C;    // big decrease
    cs[2] = fminf(fmaxf(vd, vbd + EPS_C), -EPS_C);  // decrease (clip)
    cs[3] = vs;                                     // same
    cs[4] = fminf(fmaxf(vi, EPS_C), vbi - EPS_C);   // increase (clip)
    cs[5] = fmaxf(vbi, fmaxf(0.0f, vi) + EPS_C);    // big increase
    cs[6] = 0.0f; cs[7] = 0.0f;
    s_bid = (int)atomicAdd(ticket, 1u);             // ticket => lookback progress
  }                                                 //   independent of dispatch order
  __syncthreads();
  const int bid = s_bid;

  // ---- phase A: streaming load, pack 4b/elem into regs, block total ----
  unsigned pk0 = 0, pk1 = 0, pk2 = 0, pk3 = 0;
  float tsum = 0.0f;
  const i4* in4 = (const i4*)ann + ((size_t)bid * (CHUNK / 4) + wid * 512 + lane);
#pragma unroll
  for (int r = 0; r < 8; ++r) {
    i4 v = __builtin_nontemporal_load(&in4[r * 64]);
    tsum += cs[v.x] + cs[v.y] + cs[v.z] + cs[v.w];
    unsigned nib = (unsigned)v.x | ((unsigned)v.y << 4) |
                   ((unsigned)v.z << 8) | ((unsigned)v.w << 12);
    unsigned sh = (unsigned)(r & 1) * 16u;
    if (r < 2)      pk0 |= nib << sh;
    else if (r < 4) pk1 |= nib << sh;
    else if (r < 6) pk2 |= nib << sh;
    else            pk3 |= nib << sh;
  }
#pragma unroll
  for (int off = 32; off >= 1; off >>= 1) tsum += __shfl_xor(tsum, off, 64);
  if (lane == 0) wsum[wid] = tsum;
  __syncthreads();

  // ---- lookback (wave 0 only; 64-wide window) ----
  if (wid == 0) {
    const float total = wsum[0] + wsum[1] + wsum[2] + wsum[3];
    float excl = 0.0f;
    if (bid == 0) {
      if (lane == 0) {
        __hip_atomic_store(&desc[0],
            (FLAG_INC << 32) | (unsigned long long)__float_as_uint(total),
            __ATOMIC_RELEASE, __HIP_MEMORY_SCOPE_AGENT);
        s_carry = 0.0f;
      }
    } else {
      if (lane == 0)
        __hip_atomic_store(&desc[bid],
            (FLAG_AGG << 32) | (unsigned long long)__float_as_uint(total),
            __ATOMIC_RELEASE, __HIP_MEMORY_SCOPE_AGENT);
      int look = bid;
      for (;;) {
        const int idx = look - 1 - lane;   // lane 0 reads nearest predecessor
        unsigned long long d0 = (idx >= 0)
            ? __hip_atomic_load(&desc[idx], __ATOMIC_ACQUIRE, __HIP_MEMORY_SCOPE_AGENT)
            : (FLAG_INC << 32);            // value 0.0f, terminates window
        const unsigned flag = (unsigned)(d0 >> 32);
        const unsigned long long binc = __ballot(flag == 2u);
        const unsigned long long bnone = __ballot(flag == 0u);
        const int fi = binc ? (__ffsll((long long)binc) - 1) : 64;
        const int fn = bnone ? (__ffsll((long long)bnone) - 1) : 64;
        if (fi < fn) {   // hit an INCLUSIVE before any unpublished slot
          float v = (lane <= fi) ? __uint_as_float((unsigned)d0) : 0.0f;
#pragma unroll
          for (int off = 32; off >= 1; off >>= 1) v += __shfl_xor(v, off, 64);
          excl += v;
          break;
        }
        if (fn > 0) {    // consume fn aggregates, slide the window back
          float v = (lane < fn) ? __uint_as_float((unsigned)d0) : 0.0f;
#pragma unroll
          for (int off = 32; off >= 1; off >>= 1) v += __shfl_xor(v, off, 64);
          excl += v;
          look -= fn;
        } else {
          __builtin_amdgcn_s_sleep(1);
        }
      }
      if (lane == 0) {
        __hip_atomic_store(&desc[bid],
            (FLAG_INC << 32) | (unsigned long long)__float_as_uint(excl + total),
            __ATOMIC_RELEASE, __HIP_MEMORY_SCOPE_AGENT);
        s_carry = excl;
      }
    }
    if (lane == 0 && bid == nb - 1)
      out[(size_t)nb * CHUNK] = *origin + excl + total;   // out[N]
  }
  __syncthreads();

  // ---- phase B: decode, per-wave scan (no further syncs), NT store ----
  float c = *origin + s_carry;
  if (wid > 0) c += wsum[0];
  if (wid > 1) c += wsum[1];
  if (wid > 2) c += wsum[2];
  float* ob = out + (size_t)bid * CHUNK + wid * 2048 + lane * 4;
#pragma unroll
  for (int r = 0; r < 8; ++r) {
    const unsigned pkr = (r < 2) ? pk0 : (r < 4) ? pk1 : (r < 6) ? pk2 : pk3;
    const unsigned nib = (pkr >> ((r & 1) * 16)) & 0xFFFFu;
    const float v0 = cs[nib & 0xFu];
    const float v1 = cs[(nib >> 4) & 0xFu];
    const float v2 = cs[(nib >> 8) & 0xFu];
    const float v3 = cs[(nib >> 12) & 0xFu];
    const float s4 = v0 + v1 + v2 + v3;
    float x = s4;                      // inclusive wave scan of 4-elem sums
#pragma unroll
    for (int off = 1; off < 64; off <<= 1) {
      float y = __shfl_up(x, off, 64);
      if (lane >= off) x += y;
    }
    const float off0 = c + (x - s4);   // exclusive prefix for this 4-group
    f4 o;
    o.x = off0;
    o.y = off0 + v0;
    o.z = o.y + v1;
    o.w = o.z + v2;
    __builtin_nontemporal_store(o, (f4*)(ob + r * 256));
    c += __shfl(x, 63, 64);            // wave round total -> next round carry
  }
}

extern "C" void kernel_launch(void* const* d_in, const int* in_sizes, int n_in,
                              void* d_out, int out_size, void* d_ws, size_t ws_size,
                              hipStream_t stream) {
  const int*   ann    = (const int*)d_in[0];
  const float* origin = (const float*)d_in[1];
  const float* bd     = (const float*)d_in[2];
  const float* dw     = (const float*)d_in[3];
  const float* sw     = (const float*)d_in[4];
  const float* ic     = (const float*)d_in[5];
  const float* bi     = (const float*)d_in[6];
  float* out = (float*)d_out;

  const int N  = in_sizes[0];   // 2^25
  const int nb = N / CHUNK;     // 4096 blocks

  unsigned long long* desc = (unsigned long long*)d_ws;   // nb descriptors
  unsigned int* ticket = (unsigned int*)(desc + nb);      // +1 slot: ticket

  k_zero<<<(nb + 1 + 255) / 256, 256, 0, stream>>>(desc, nb + 1);
  k_scan_lookback<<<nb, BLOCK, 0, stream>>>(ann, origin, bd, dw, sw, ic, bi,
                                            out, desc, ticket, nb);
}

// Round 4
// 248.104 us; speedup vs baseline: 2.8284x; 2.8284x over previous
//
#include <hip/hip_runtime.h>

#define EPS_C 0.05f

typedef int i4 __attribute__((ext_vector_type(4)));
typedef float f4 __attribute__((ext_vector_type(4)));

// Build the 6-entry change table into LDS (thread 0 only; caller syncs).
__device__ __forceinline__ void build_table(const float* bd_p, const float* d_p,
                                            const float* s_p, const float* inc_p,
                                            const float* bi_p, float* cs) {
  if (threadIdx.x == 0) {
    float bd = *bd_p, d = *d_p, s = *s_p, inc = *inc_p, bi = *bi_p;
    cs[0] = 0.0f;                                   // cat 0 (unused)
    cs[1] = fminf(bd, fminf(0.0f, d)) - EPS_C;      // big decrease
    cs[2] = fminf(fmaxf(d, bd + EPS_C), -EPS_C);    // decrease (clip)
    cs[3] = s;                                      // same
    cs[4] = fminf(fmaxf(inc, EPS_C), bi - EPS_C);   // increase (clip)
    cs[5] = fmaxf(bi, fmaxf(0.0f, inc) + EPS_C);    // big increase
    cs[6] = 0.0f; cs[7] = 0.0f;
  }
}

// P1: block b owns 8192 elems (4 waves x 2048). Wave round r: lane l loads
// i4 at elem wbase + r*256 + l*4 (16B/lane, perfectly coalesced, NT read-once).
// Emits nibble-pack (element order: ushort g covers elems [4g,4g+4)) and one
// fine sum per 1024 elems (2 per wave).
__global__ __launch_bounds__(256) void k_pack_reduce(
    const int* __restrict__ ann, const float* bd, const float* d,
    const float* s, const float* inc, const float* bi,
    unsigned short* __restrict__ pack, float* __restrict__ fine) {
  __shared__ float cs[8];
  build_table(bd, d, s, inc, bi, cs);
  __syncthreads();
  const int t = threadIdx.x, lane = t & 63, w = t >> 6, b = blockIdx.x;
  const size_t ebase = (size_t)b * 8192 + w * 2048;     // wave's first elem
  const i4* in4 = (const i4*)ann + (ebase >> 2) + lane; // i4 index = elem/4
  unsigned short* pk = pack + (ebase >> 2) + lane;      // ushort idx = elem/4
  float fs0 = 0.0f, fs1 = 0.0f;                         // fine sums (rounds 0-3 / 4-7)
#pragma unroll
  for (int r = 0; r < 8; ++r) {
    i4 v = __builtin_nontemporal_load(&in4[r * 64]);
    float e = cs[v.x] + cs[v.y] + cs[v.z] + cs[v.w];
    if (r < 4) fs0 += e; else fs1 += e;
    unsigned us = (unsigned)v.x | ((unsigned)v.y << 4) |
                  ((unsigned)v.z << 8) | ((unsigned)v.w << 12);
    pk[r * 64] = (unsigned short)us;                    // cached (P2 re-reads)
  }
#pragma unroll
  for (int off = 32; off >= 1; off >>= 1) {
    fs0 += __shfl_xor(fs0, off, 64);
    fs1 += __shfl_xor(fs1, off, 64);
  }
  if (lane == 0) {
    fine[b * 8 + w * 2 + 0] = fs0;
    fine[b * 8 + w * 2 + 1] = fs1;
  }
}

// P1.5: single block, exclusive scan (seeded with origin) of the 32768 fine
// sums -> fine_pref. Thread t owns 32 contiguous values. Also writes out[N].
__global__ __launch_bounds__(1024) void k_scan_fine(
    const float* __restrict__ fine, const float* __restrict__ origin,
    float* __restrict__ pref, float* __restrict__ outN) {
  __shared__ float ws[16];
  const int t = threadIdx.x, lane = t & 63, w = t >> 6;
  float v[32];
  const f4* fv = (const f4*)fine + t * 8;
  float tot = 0.0f;
#pragma unroll
  for (int i = 0; i < 8; ++i) {
    f4 x = fv[i];
    v[i * 4 + 0] = x.x; v[i * 4 + 1] = x.y;
    v[i * 4 + 2] = x.z; v[i * 4 + 3] = x.w;
    tot += x.x + x.y + x.z + x.w;
  }
  float x = tot;                      // inclusive wave scan of thread totals
#pragma unroll
  for (int off = 1; off < 64; off <<= 1) {
    float y = __shfl_up(x, off, 64);
    if (lane >= off) x += y;
  }
  if (lane == 63) ws[w] = x;
  __syncthreads();
  float wexcl = 0.0f;
#pragma unroll
  for (int i = 0; i < 16; ++i) { float wv = ws[i]; if (i < w) wexcl += wv; }
  float run = *origin + wexcl + (x - tot);   // exclusive prefix before thread t
#pragma unroll
  for (int i = 0; i < 8; ++i) {
    f4 o;
    o.x = run; run += v[i * 4 + 0];
    o.y = run; run += v[i * 4 + 1];
    o.z = run; run += v[i * 4 + 2];
    o.w = run; run += v[i * 4 + 3];
    ((f4*)pref)[t * 8 + i] = o;
  }
  if (t == 1023) *outN = run;                // origin + total = out[N]
}

// P2: barrier-free after table build. Each wave owns 2 independent 1024-elem
// units; per unit: offset = fine_pref[u] (1 scalar load), 4 rounds of
// {ushort decode -> 64-lane scan -> float4 NT store (1 KiB/wave, full-line)}.
__global__ __launch_bounds__(256) void k_scan_out(
    const unsigned short* __restrict__ pack, const float* __restrict__ pref,
    const float* bd, const float* d, const float* s, const float* inc,
    const float* bi, float* __restrict__ out) {
  __shared__ float cs[8];
  build_table(bd, d, s, inc, bi, cs);
  __syncthreads();
  const int t = threadIdx.x, lane = t & 63, w = t >> 6, b = blockIdx.x;
#pragma unroll
  for (int h = 0; h < 2; ++h) {
    const int u = b * 8 + w * 2 + h;                    // fine unit id
    const size_t ebase = (size_t)u * 1024;
    const unsigned short* pk = pack + (ebase >> 2) + lane;
    unsigned short us0 = pk[0], us1 = pk[64], us2 = pk[128], us3 = pk[192];
    float carry = pref[u];
    unsigned short usv[4] = {us0, us1, us2, us3};
#pragma unroll
    for (int r = 0; r < 4; ++r) {
      const unsigned us = usv[r];
      const float v0 = cs[us & 0xFu];
      const float v1 = cs[(us >> 4) & 0xFu];
      const float v2 = cs[(us >> 8) & 0xFu];
      const float v3 = cs[(us >> 12) & 0xFu];
      const float s4 = v0 + v1 + v2 + v3;
      float x = s4;                   // inclusive wave scan of 4-elem sums
#pragma unroll
      for (int off = 1; off < 64; off <<= 1) {
        float y = __shfl_up(x, off, 64);
        if (lane >= off) x += y;
      }
      const float off0 = carry + (x - s4);  // exclusive prefix for this 4-group
      f4 o;
      o.x = off0;
      o.y = off0 + v0;
      o.z = o.y + v1;
      o.w = o.z + v2;
      __builtin_nontemporal_store(o, (f4*)(out + ebase + r * 256 + lane * 4));
      carry += __shfl(x, 63, 64);     // round total -> next round
    }
  }
}

extern "C" void kernel_launch(void* const* d_in, const int* in_sizes, int n_in,
                              void* d_out, int out_size, void* d_ws, size_t ws_size,
                              hipStream_t stream) {
  const int*   ann    = (const int*)d_in[0];
  const float* origin = (const float*)d_in[1];
  const float* bd     = (const float*)d_in[2];
  const float* dw     = (const float*)d_in[3];
  const float* sw     = (const float*)d_in[4];
  const float* ic     = (const float*)d_in[5];
  const float* bi     = (const float*)d_in[6];
  float* out = (float*)d_out;

  const int N   = in_sizes[0];    // 2^25
  const int nb  = N / 8192;       // 4096 blocks (P1 and P2)
  const int nf  = N / 1024;       // 32768 fine units

  float* fine = (float*)d_ws;                             // 32768 floats
  float* pref = fine + nf;                                // 32768 floats
  unsigned short* pack = (unsigned short*)(pref + nf);    // 16.8 MB

  k_pack_reduce<<<nb, 256, 0, stream>>>(ann, bd, dw, sw, ic, bi, pack, fine);
  k_scan_fine<<<1, 1024, 0, stream>>>(fine, origin, pref, out + N);
  k_scan_out<<<nb, 256, 0, stream>>>(pack, pref, bd, dw, sw, ic, bi, out);
}